// Round 1
// baseline (569.678 us; speedup 1.0000x reference)
//
#include <hip/hip_runtime.h>

typedef __bf16 bf16x8 __attribute__((ext_vector_type(8)));
typedef float f32x4 __attribute__((ext_vector_type(4)));
typedef unsigned short us8 __attribute__((ext_vector_type(8)));

constexpr int NN = 50000;   // nodes
constexpr int NE = 800000;  // edges
constexpr int DIN = 256, DHID = 256, DOUT = 128;
constexpr int NCH = (NN + 255) / 256;  // 196 chunks of 256

__device__ __forceinline__ unsigned short f2bf(float f) {
  unsigned u = __float_as_uint(f);
  u += 0x7fffu + ((u >> 16) & 1u);  // RNE
  return (unsigned short)(u >> 16);
}
__device__ __forceinline__ float bf2f(unsigned short h) {
  return __uint_as_float(((unsigned)h) << 16);
}

// accumulate 8 bf16 (packed in uint4) into a[8]
__device__ __forceinline__ void acc8(float a[8], uint4 v) {
  a[0] += __uint_as_float(v.x << 16);
  a[1] += __uint_as_float(v.x & 0xffff0000u);
  a[2] += __uint_as_float(v.y << 16);
  a[3] += __uint_as_float(v.y & 0xffff0000u);
  a[4] += __uint_as_float(v.z << 16);
  a[5] += __uint_as_float(v.z & 0xffff0000u);
  a[6] += __uint_as_float(v.w << 16);
  a[7] += __uint_as_float(v.w & 0xffff0000u);
}
__device__ __forceinline__ void acc8m(float a[8], uint4 v, float m) {
  a[0] = fmaf(m, __uint_as_float(v.x << 16), a[0]);
  a[1] = fmaf(m, __uint_as_float(v.x & 0xffff0000u), a[1]);
  a[2] = fmaf(m, __uint_as_float(v.y << 16), a[2]);
  a[3] = fmaf(m, __uint_as_float(v.y & 0xffff0000u), a[3]);
  a[4] = fmaf(m, __uint_as_float(v.z << 16), a[4]);
  a[5] = fmaf(m, __uint_as_float(v.z & 0xffff0000u), a[5]);
  a[6] = fmaf(m, __uint_as_float(v.w << 16), a[6]);
  a[7] = fmaf(m, __uint_as_float(v.w & 0xffff0000u), a[7]);
}

// ---------------- CSR build ----------------

__global__ void hist_kernel(const int* __restrict__ e0, const int* __restrict__ e1,
                            int* __restrict__ counts) {
  int g = blockIdx.y;
  const int* dst = (g ? e1 : e0) + NE;  // edge_index row 1
  int* c = counts + g * NN;
  int i = blockIdx.x * blockDim.x + threadIdx.x;
  if (i < NE) atomicAdd(&c[dst[i]], 1);
}

// 3-phase hierarchical exclusive scan of counts -> rowptr/cursor (+dinv)

__global__ __launch_bounds__(256) void scanA_kernel(const int* __restrict__ counts,
                                                    int* __restrict__ bsum) {
  int g = blockIdx.y, chunk = blockIdx.x, t = threadIdx.x;
  int i = chunk * 256 + t;
  int v = (i < NN) ? counts[g * NN + i] : 0;
  __shared__ int sh[256];
  sh[t] = v;
  __syncthreads();
  for (int off = 128; off > 0; off >>= 1) {
    if (t < off) sh[t] += sh[t + off];
    __syncthreads();
  }
  if (t == 0) bsum[g * NCH + chunk] = sh[0];
}

__global__ __launch_bounds__(256) void scanB_kernel(int* __restrict__ bsum,
                                                    int* __restrict__ rowptr) {
  int g = blockIdx.x, t = threadIdx.x;
  int v = (t < NCH) ? bsum[g * NCH + t] : 0;
  __shared__ int sh[256];
  sh[t] = v;
  __syncthreads();
  for (int off = 1; off < 256; off <<= 1) {
    int x = (t >= off) ? sh[t - off] : 0;
    __syncthreads();
    if (t >= off) sh[t] += x;
    __syncthreads();
  }
  if (t < NCH) bsum[g * NCH + t] = sh[t] - v;  // exclusive base
  if (t == 255) rowptr[g * (NN + 1) + NN] = sh[255];
}

__global__ __launch_bounds__(256) void scanC_kernel(const int* __restrict__ counts,
                                                    const int* __restrict__ bsum,
                                                    int* __restrict__ rowptr,
                                                    int* __restrict__ cursor,
                                                    float* __restrict__ dinv) {
  int g = blockIdx.y, chunk = blockIdx.x, t = threadIdx.x;
  int i = chunk * 256 + t;
  int v = (i < NN) ? counts[g * NN + i] : 0;
  __shared__ int sh[256];
  sh[t] = v;
  __syncthreads();
  for (int off = 1; off < 256; off <<= 1) {
    int x = (t >= off) ? sh[t - off] : 0;
    __syncthreads();
    if (t >= off) sh[t] += x;
    __syncthreads();
  }
  if (i < NN) {
    int run = bsum[g * NCH + chunk] + sh[t] - v;
    rowptr[g * (NN + 1) + i] = run;
    cursor[g * NN + i] = run;
    dinv[g * NN + i] = rsqrtf((float)(v + 1));  // +1 self-loop
  }
}

__global__ void scatter_kernel(const int* __restrict__ e0, const int* __restrict__ e1,
                               int* __restrict__ cursor, unsigned short* __restrict__ col) {
  int g = blockIdx.y;
  const int* e = g ? e1 : e0;
  int* cur = cursor + g * NN;
  unsigned short* cl = col + g * NE;
  int i = blockIdx.x * blockDim.x + threadIdx.x;
  if (i < NE) {
    int s = e[i], d = e[NE + i];
    int slot = atomicAdd(&cur[d], 1);
    cl[slot] = (unsigned short)s;
  }
}

// ---------------- Pack W into B-fragment order ----------------
// Wpack flat index: ((kb*NT + nt)*64 + lane)*8 + j  holds W[kb*32 + (lane>>4)*8 + j][nt*16 + (lane&15)]

__global__ void pack_kernel(const float* __restrict__ W1, const float* __restrict__ W2,
                            unsigned short* __restrict__ P1, unsigned short* __restrict__ P2) {
  int i = blockIdx.x * blockDim.x + threadIdx.x;
  constexpr int N1 = 8 * 16 * 64 * 8;  // 65536 (K=256, N=256)
  constexpr int N2 = 8 * 8 * 64 * 8;   // 32768 (K=256, N=128)
  if (i < N1) {
    int j = i & 7, lane = (i >> 3) & 63, grp = i >> 9;
    int nt = grp & 15, kb = grp >> 4;
    int k = kb * 32 + (lane >> 4) * 8 + j;
    int n = nt * 16 + (lane & 15);
    P1[i] = f2bf(W1[k * DHID + n]);
  } else if (i < N1 + N2) {
    int ii = i - N1;
    int j = ii & 7, lane = (ii >> 3) & 63, grp = ii >> 9;
    int nt = grp & 7, kb = grp >> 3;
    int k = kb * 32 + (lane >> 4) * 8 + j;
    int n = nt * 16 + (lane & 15);
    P2[ii] = f2bf(W2[k * DOUT + n]);
  }
}

// ---------------- MFMA matmul (layer 1): m1 = (x @ W1) * dinv[row] ----------------

__global__ __launch_bounds__(256) void mm1_kernel(
    const float* __restrict__ A0, const float* __restrict__ A1,
    const unsigned short* __restrict__ Wp, unsigned short* __restrict__ Cb,
    const float* __restrict__ dinv) {
  constexpr int N = DHID, NT = N / 16, K = 256;
  int g = blockIdx.y;
  const float* A = g ? A1 : A0;
  unsigned short* C = Cb + (size_t)g * NN * N;
  const float* dv = dinv + g * NN;
  int wave = threadIdx.x >> 6, lane = threadIdx.x & 63;
  int q = lane >> 4, lm = lane & 15;
  int m0 = blockIdx.x * 64 + wave * 16;
  int rowc = min(m0 + lm, NN - 1);
  f32x4 acc[NT];
#pragma unroll
  for (int nt = 0; nt < NT; nt++) acc[nt] = (f32x4){0.f, 0.f, 0.f, 0.f};
#pragma unroll
  for (int kb = 0; kb < K / 32; kb++) {
    int kc = kb * 32 + q * 8;  // lane's contiguous k-chunk (A frag: k = quad*8+j)
    const float* Af = A + (size_t)rowc * K + kc;
    const float4 v0 = *(const float4*)Af;
    const float4 v1 = *(const float4*)(Af + 4);
    bf16x8 a;
    a[0] = (__bf16)v0.x; a[1] = (__bf16)v0.y; a[2] = (__bf16)v0.z; a[3] = (__bf16)v0.w;
    a[4] = (__bf16)v1.x; a[5] = (__bf16)v1.y; a[6] = (__bf16)v1.z; a[7] = (__bf16)v1.w;
#pragma unroll
    for (int nt = 0; nt < NT; nt++) {
      bf16x8 b = *(const bf16x8*)(Wp + (((size_t)kb * NT + nt) * 64 + lane) * 8);
      acc[nt] = __builtin_amdgcn_mfma_f32_16x16x32_bf16(a, b, acc[nt], 0, 0, 0);
    }
  }
  // C/D layout: col = lane&15, row = quad*4 + reg
  float dvr[4];
#pragma unroll
  for (int r = 0; r < 4; r++) dvr[r] = dv[min(m0 + q * 4 + r, NN - 1)];
#pragma unroll
  for (int nt = 0; nt < NT; nt++) {
#pragma unroll
    for (int r = 0; r < 4; r++) {
      int grow = m0 + q * 4 + r;
      if (grow < NN) C[(size_t)grow * N + nt * 16 + lm] = f2bf(acc[nt][r] * dvr[r]);
    }
  }
}

// ---------- Fused agg1 + mm2: block = 16 nodes ----------
// Phase 1 (wide-gather form): each wave aggregates 4 nodes serially. Gather
// uses 16 B/lane: half-wave h (32 lanes) covers row s[2u+h], lane li=lane&31
// covers cols li*8..li*8+7. One dwordx4 instruction fetches TWO rows (1 KiB)
// -> half the VMEM instructions + half the address VALU vs 8 B/lane form.
// Per-node epilogue: 8x shfl_xor(32) combines the even/odd-row halves.
// Result (= relu((agg+self)*dinv + b1)) goes to LDS bf16 (stride padded +8).
// Phase 2: 16x128 MFMA tile vs packed W2; epilogue prescales by dinv[row].

__global__ __launch_bounds__(256) void agg1mm2_kernel(
    const unsigned short* __restrict__ m1b, const unsigned short* __restrict__ P2,
    unsigned short* __restrict__ m2b, const int* __restrict__ rowptr,
    const unsigned short* __restrict__ col, const float* __restrict__ dinv,
    const float* __restrict__ b1) {
  constexpr int LDW = DHID + 8;  // 264 elem = 528 B row stride
  __shared__ unsigned short sha[16 * LDW];
  int g = blockIdx.y;
  const unsigned short* H = m1b + (size_t)g * NN * DHID;
  unsigned short* M2 = m2b + (size_t)g * NN * DOUT;
  const int* rp = rowptr + g * (NN + 1);
  const unsigned short* cl = col + (size_t)g * NE;
  const float* dv = dinv + g * NN;
  int wave = threadIdx.x >> 6, lane = threadIdx.x & 63;
  int half = lane >> 5, li = lane & 31;  // li covers cols li*8..+7
  int base = blockIdx.x * 16;
  float4 bb0 = *(const float4*)(b1 + li * 8);
  float4 bb1 = *(const float4*)(b1 + li * 8 + 4);
  // ---- phase 1: gather-aggregate 4 nodes per wave, 2 rows per load instr ----
  for (int n = 0; n < 4; n++) {
    int node = base + wave * 4 + n;
    float a[8] = {0.f, 0.f, 0.f, 0.f, 0.f, 0.f, 0.f, 0.f};
    if (half == 0) {  // self row, counted once (half 1 contributes 0)
      uint4 sv = *(const uint4*)(H + (size_t)node * DHID + li * 8);
      acc8(a, sv);
    }
    int jb = rp[node], je = rp[node + 1];
    int j = jb;
    for (; j + 16 <= je; j += 16) {
      int s[16];
#pragma unroll
      for (int u = 0; u < 16; u++) s[u] = cl[j + u];
      uint4 v[8];
#pragma unroll
      for (int u = 0; u < 8; u++)
        v[u] = *(const uint4*)(H + (size_t)s[2 * u + half] * DHID + li * 8);
#pragma unroll
      for (int u = 0; u < 8; u++) acc8(a, v[u]);
    }
    for (; j + 8 <= je; j += 8) {
      int s[8];
#pragma unroll
      for (int u = 0; u < 8; u++) s[u] = cl[j + u];
      uint4 v[4];
#pragma unroll
      for (int u = 0; u < 4; u++)
        v[u] = *(const uint4*)(H + (size_t)s[2 * u + half] * DHID + li * 8);
#pragma unroll
      for (int u = 0; u < 4; u++) acc8(a, v[u]);
    }
    for (; j < je; j += 2) {  // masked 2-row tail
      int idx = j + half;
      int sidx = cl[min(idx, je - 1)];
      uint4 v = *(const uint4*)(H + (size_t)sidx * DHID + li * 8);
      float m = (idx < je) ? 1.f : 0.f;
      acc8m(a, v, m);
    }
    // combine even-row half with odd-row half
#pragma unroll
    for (int i = 0; i < 8; i++) a[i] += __shfl_xor(a[i], 32, 64);
    float di = dv[node];
    float r0 = fmaxf(fmaf(a[0], di, bb0.x), 0.f);
    float r1 = fmaxf(fmaf(a[1], di, bb0.y), 0.f);
    float r2 = fmaxf(fmaf(a[2], di, bb0.z), 0.f);
    float r3 = fmaxf(fmaf(a[3], di, bb0.w), 0.f);
    float r4 = fmaxf(fmaf(a[4], di, bb1.x), 0.f);
    float r5 = fmaxf(fmaf(a[5], di, bb1.y), 0.f);
    float r6 = fmaxf(fmaf(a[6], di, bb1.z), 0.f);
    float r7 = fmaxf(fmaf(a[7], di, bb1.w), 0.f);
    us8 o;
    o[0] = f2bf(r0); o[1] = f2bf(r1); o[2] = f2bf(r2); o[3] = f2bf(r3);
    o[4] = f2bf(r4); o[5] = f2bf(r5); o[6] = f2bf(r6); o[7] = f2bf(r7);
    if (half == 0) *(us8*)(sha + (wave * 4 + n) * LDW + li * 8) = o;
  }
  __syncthreads();
  // ---- phase 2: 16x128 tile = A(16x256 from LDS) @ W2 ----
  int q = lane >> 4, lm = lane & 15;
  f32x4 acc[2];
  acc[0] = (f32x4){0.f, 0.f, 0.f, 0.f};
  acc[1] = (f32x4){0.f, 0.f, 0.f, 0.f};
  constexpr int NT2 = DOUT / 16;  // 8
#pragma unroll
  for (int kb = 0; kb < 8; kb++) {
    bf16x8 a = *(const bf16x8*)(sha + lm * LDW + kb * 32 + q * 8);
#pragma unroll
    for (int t = 0; t < 2; t++) {
      int nt = wave * 2 + t;
      bf16x8 b = *(const bf16x8*)(P2 + (((size_t)kb * NT2 + nt) * 64 + lane) * 8);
      acc[t] = __builtin_amdgcn_mfma_f32_16x16x32_bf16(a, b, acc[t], 0, 0, 0);
    }
  }
  float dvr[4];
#pragma unroll
  for (int r = 0; r < 4; r++) dvr[r] = dv[base + q * 4 + r];
#pragma unroll
  for (int t = 0; t < 2; t++) {
#pragma unroll
    for (int r = 0; r < 4; r++) {
      int node = base + q * 4 + r;
      M2[(size_t)node * DOUT + (wave * 2 + t) * 16 + lm] = f2bf(acc[t][r] * dvr[r]);
    }
  }
}

// ---------------- agg2 (wide-gather): gather m2, +self, *dinv, +bias -> out ----
// One node per wave. 16 B/lane: group grp=lane>>4 (4 groups of 16 lanes) covers
// row s[4u+grp]; li=lane&15 covers cols li*8..+7 (256 B row = 16 lanes x 16 B).
// One dwordx4 instruction fetches FOUR rows. Final: shfl_xor(16)+shfl_xor(32).

__global__ __launch_bounds__(256) void agg2_kernel(
    const unsigned short* __restrict__ m2, float* __restrict__ out,
    const int* __restrict__ rowptr, const unsigned short* __restrict__ col,
    const float* __restrict__ dinv, const float* __restrict__ b2) {
  int g = blockIdx.y;
  const unsigned short* H = m2 + (size_t)g * NN * DOUT;
  float* O = out + (size_t)g * NN * DOUT;
  const int* rp = rowptr + g * (NN + 1);
  const unsigned short* cl = col + (size_t)g * NE;
  const float* dv = dinv + g * NN;
  int node = blockIdx.x * 4 + (threadIdx.x >> 6);
  int lane = threadIdx.x & 63;
  int grp = lane >> 4, li = lane & 15;  // li covers cols li*8..+7
  float4 c0 = *(const float4*)(b2 + li * 8);
  float4 c1 = *(const float4*)(b2 + li * 8 + 4);
  float a[8] = {0.f, 0.f, 0.f, 0.f, 0.f, 0.f, 0.f, 0.f};
  if (grp == 0) {  // self row, counted once
    uint4 sv = *(const uint4*)(H + (size_t)node * DOUT + li * 8);
    acc8(a, sv);
  }
  int jb = rp[node], je = rp[node + 1];
  int j = jb;
  for (; j + 16 <= je; j += 16) {
    int s[16];
#pragma unroll
    for (int u = 0; u < 16; u++) s[u] = cl[j + u];
    uint4 v[4];
#pragma unroll
    for (int u = 0; u < 4; u++)
      v[u] = *(const uint4*)(H + (size_t)s[4 * u + grp] * DOUT + li * 8);
#pragma unroll
    for (int u = 0; u < 4; u++) acc8(a, v[u]);
  }
  for (; j < je; j += 4) {  // masked 4-row tail
    int idx = j + grp;
    int sidx = cl[min(idx, je - 1)];
    uint4 v = *(const uint4*)(H + (size_t)sidx * DOUT + li * 8);
    float m = (idx < je) ? 1.f : 0.f;
    acc8m(a, v, m);
  }
  // combine the 4 row-groups
#pragma unroll
  for (int i = 0; i < 8; i++) a[i] += __shfl_xor(a[i], 16, 64);
#pragma unroll
  for (int i = 0; i < 8; i++) a[i] += __shfl_xor(a[i], 32, 64);
  if (grp == 0) {
    float di = dv[node];
    float4 o0, o1;
    o0.x = fmaf(a[0], di, c0.x); o0.y = fmaf(a[1], di, c0.y);
    o0.z = fmaf(a[2], di, c0.z); o0.w = fmaf(a[3], di, c0.w);
    o1.x = fmaf(a[4], di, c1.x); o1.y = fmaf(a[5], di, c1.y);
    o1.z = fmaf(a[6], di, c1.z); o1.w = fmaf(a[7], di, c1.w);
    *(float4*)(O + (size_t)node * DOUT + li * 8) = o0;
    *(float4*)(O + (size_t)node * DOUT + li * 8 + 4) = o1;
  }
}

// ---------------- launch ----------------

extern "C" void kernel_launch(void* const* d_in, const int* in_sizes, int n_in,
                              void* d_out, int out_size, void* d_ws, size_t ws_size,
                              hipStream_t stream) {
  const float* x1 = (const float*)d_in[0];
  const int* e1 = (const int*)d_in[1];
  const float* x2 = (const float*)d_in[2];
  const int* e2 = (const int*)d_in[3];
  const float* W1 = (const float*)d_in[4];
  const float* b1 = (const float*)d_in[5];
  const float* W2 = (const float*)d_in[6];
  const float* b2 = (const float*)d_in[7];
  float* out = (float*)d_out;

  char* base = (char*)d_ws;
  size_t off = 0;
  auto alloc = [&](size_t bytes) -> void* {
    void* p = base + off;
    off = (off + bytes + 511) & ~(size_t)511;
    return p;
  };
  int* counts = (int*)alloc((size_t)2 * NN * 4);
  int* rowptr = (int*)alloc((size_t)2 * (NN + 1) * 4);
  int* cursor = (int*)alloc((size_t)2 * NN * 4);
  float* dinv = (float*)alloc((size_t)2 * NN * 4);
  int* bsum = (int*)alloc((size_t)2 * NCH * 4);
  unsigned short* col = (unsigned short*)alloc((size_t)2 * NE * 2);
  unsigned short* m1 = (unsigned short*)alloc((size_t)2 * NN * DHID * 2);
  unsigned short* m2 = (unsigned short*)alloc((size_t)2 * NN * DOUT * 2);
  unsigned short* P1 = (unsigned short*)alloc((size_t)8 * 16 * 64 * 8 * 2);
  unsigned short* P2 = (unsigned short*)alloc((size_t)8 * 8 * 64 * 8 * 2);

  hipMemsetAsync(counts, 0, (size_t)2 * NN * 4, stream);
  hist_kernel<<<dim3((NE + 255) / 256, 2), 256, 0, stream>>>(e1, e2, counts);
  scanA_kernel<<<dim3(NCH, 2), 256, 0, stream>>>(counts, bsum);
  scanB_kernel<<<2, 256, 0, stream>>>(bsum, rowptr);
  scanC_kernel<<<dim3(NCH, 2), 256, 0, stream>>>(counts, bsum, rowptr, cursor, dinv);
  scatter_kernel<<<dim3((NE + 255) / 256, 2), 256, 0, stream>>>(e1, e2, cursor, col);
  pack_kernel<<<(98304 + 255) / 256, 256, 0, stream>>>(W1, W2, P1, P2);
  // layer 1 mm: m1 = (x @ W1) * dinv (bf16)
  mm1_kernel<<<dim3((NN + 63) / 64, 2), 256, 0, stream>>>(x1, x2, P1, m1, dinv);
  // fused: a1 = relu(agg(m1)*dinv + b1) -> LDS -> m2 = (a1 @ W2) * dinv
  agg1mm2_kernel<<<dim3(NN / 16, 2), 256, 0, stream>>>(m1, P2, m2, rowptr, col, dinv, b1);
  // layer 2 agg: out = agg(m2)*dinv + b2 (fp32)
  agg2_kernel<<<dim3(NN / 4, 2), 256, 0, stream>>>(m2, out, rowptr, col, dinv, b2);
}